// Round 1
// baseline (95.082 us; speedup 1.0000x reference)
//
#include <hip/hip_runtime.h>
#include <hip/hip_bf16.h>

typedef __attribute__((ext_vector_type(8))) short short8;
typedef __attribute__((ext_vector_type(4))) float f32x4;

#define PATH_W 0.0625f
#define INV_SQRT3 0.57735026918962576f

__device__ __forceinline__ unsigned short f2bf(float f) {
    unsigned int u = __builtin_bit_cast(unsigned int, f);
    u += 0x7FFFu + ((u >> 16) & 1u);   // round-to-nearest-even
    return (unsigned short)(u >> 16);
}

__device__ __forceinline__ float silu(float x) {
    return x / (1.0f + __expf(-x));
}

// ---------------------------------------------------------------------------
// Prep: block 0 computes the 5 per-channel coefficient vectors
//   A_q = wq_s @ Wq0, B_q = wq_s @ bq, A_v = wv_s @ Wv0, B_v = wv_s @ bv,
//   Av1 = wv_v @ Wv1       (each [128] f32, stored at ws[0..640))
// Blocks 1..128 pack W1/W2/W3 into frag-major bf16 A-fragments for
// mfma_f32_16x16x32_bf16 with swapped operands (A = W^T):
//   frag(mt,ks) slot(lane,j) = W[(ks*32 + (lane>>4)*8 + j)*128 + mt*16 + (lane&15)]
// wp layout: fid 0..63 = W1 (mt*8+ks), 64..95 = W2 (mt*4+ks), 96..127 = W3.
// ---------------------------------------------------------------------------
__global__ void prep_all(const float* __restrict__ Wq0, const float* __restrict__ bq,
                         const float* __restrict__ Wv0, const float* __restrict__ bv,
                         const float* __restrict__ Wv1, const float* __restrict__ wq_s,
                         const float* __restrict__ wv_s, const float* __restrict__ wv_v,
                         const float* __restrict__ W1, const float* __restrict__ W2,
                         const float* __restrict__ W3,
                         float* __restrict__ vecs, unsigned short* __restrict__ wp) {
    if (blockIdx.x == 0) {
        int u = threadIdx.x;  // 0..127
        float aq = 0.f, bqs = 0.f, av = 0.f, bvs = 0.f, a1 = 0.f;
        for (int v = 0; v < 128; ++v) {
            float rq = wq_s[u * 128 + v];
            float rv = wv_s[u * 128 + v];
            aq  += Wq0[v] * rq;
            bqs += bq[v]  * rq;
            av  += Wv0[v] * rv;
            bvs += bv[v]  * rv;
            a1  += Wv1[v] * wv_v[u * 128 + v];
        }
        vecs[u]       = aq;
        vecs[128 + u] = bqs;
        vecs[256 + u] = av;
        vecs[384 + u] = bvs;
        vecs[512 + u] = a1;
        return;
    }
    int fid  = blockIdx.x - 1;      // 0..127
    int t    = threadIdx.x;         // 0..127
    int lane = t & 63;
    int half = t >> 6;
    int g  = lane >> 4;
    int r  = lane & 15;
    const float* W;
    int mt, ks;
    if (fid < 64)      { W = W1; mt = fid >> 3;        ks = fid & 7; }
    else if (fid < 96) { W = W2; mt = (fid - 64) >> 2; ks = (fid - 64) & 3; }
    else               { W = W3; mt = (fid - 96) >> 2; ks = (fid - 96) & 3; }
    int col  = mt * 16 + r;
    int row0 = ks * 32 + g * 8 + half * 4;
    unsigned short* dst = wp + fid * 512 + lane * 8 + half * 4;
    #pragma unroll
    for (int j = 0; j < 4; ++j) dst[j] = f2bf(W[(row0 + j) * 128 + col]);
}

// ---------------------------------------------------------------------------
// Fused main kernel: 8 waves x 16 nodes = 128 nodes/block.
// Swapped-operand GEMMs: D[f][n] -> lane owns node n = lane&15 throughout.
// LDS (64KB) phased: [W1 frags] -> [per-wave h1 transpose] -> [W2|W3 frags],
// h2 transpose overlays W2 after GEMM2.
// ---------------------------------------------------------------------------
__global__ __launch_bounds__(512, 4) void fused_main(
    const float* __restrict__ nf,     // node_feats [N,512]
    const float* __restrict__ field,  // field_feats [N,4]
    const float* __restrict__ c0, const float* __restrict__ ci,
    const float* __restrict__ vecs,   // 5 x 128 f32
    const unsigned short* __restrict__ wp,  // packed bf16 frags
    const float* __restrict__ W4, const float* __restrict__ b1,
    const float* __restrict__ b2, const float* __restrict__ b3,
    const float* __restrict__ b4, float* __restrict__ out, int N)
{
    __shared__ __align__(16) char smem[65536];
    const int tid  = threadIdx.x;
    const int wave = tid >> 6;
    const int lane = tid & 63;
    const int g    = lane >> 4;     // k-group within frag
    const int nl   = lane & 15;     // node-in-wave == MFMA column
    const int nd   = blockIdx.x * 128 + wave * 16 + nl;
    const int ndc  = nd < N ? nd : N - 1;

    // ---- stage W1 frags (64KB) into LDS (linear copy, coalesced) ----
    {
        const f32x4* src = reinterpret_cast<const f32x4*>(wp);
        f32x4* dst = reinterpret_cast<f32x4*>(smem);
        #pragma unroll
        for (int i = 0; i < 8; ++i) dst[tid + i * 512] = src[tid + i * 512];
    }

    // ---- per-node h computation -> GEMM1 B-fragments in registers ----
    // hfrag[ks] slot j holds h[n][ks*32 + g*8 + j]  (ks 0..3 = dot_q, 4..7 = dot_v)
    const float q_in = c0[ndc] + ci[ndc];
    const f32x4 ff   = reinterpret_cast<const f32x4*>(field)[ndc];
    const f32x4* nf4  = reinterpret_cast<const f32x4*>(nf);
    const f32x4* vec4 = reinterpret_cast<const f32x4*>(vecs);
    const int row = ndc * 128;  // node row in f32x4 units (512 floats)
    short8 hfrag[8];
    #pragma unroll
    for (int k = 0; k < 4; ++k) {
        #pragma unroll
        for (int h = 0; h < 2; ++h) {
            const int cb = 32 * k + 8 * g + 4 * h;   // channel base (mult of 4)
            const int m  = cb >> 2;
            f32x4 s  = nf4[row + m];
            f32x4 va = nf4[row + 32 + 3 * m];
            f32x4 vb = nf4[row + 32 + 3 * m + 1];
            f32x4 vc = nf4[row + 32 + 3 * m + 2];
            f32x4 aq = vec4[m], bqv = vec4[32 + m], av = vec4[64 + m],
                  bvv = vec4[96 + m], a1 = vec4[128 + m];
            float vx[4], vy[4], vz[4];
            vx[0] = va[0]; vy[0] = va[1]; vz[0] = va[2];
            vx[1] = va[3]; vy[1] = vb[0]; vz[1] = vb[1];
            vx[2] = vb[2]; vy[2] = vb[3]; vz[2] = vc[0];
            vx[3] = vc[1]; vy[3] = vc[2]; vz[3] = vc[3];
            #pragma unroll
            for (int j = 0; j < 4; ++j) {
                float sc = s[j];
                float hq = PATH_W * sc * (q_in * aq[j] + bqv[j]);
                float d3 = vx[j] * ff[1] + vy[j] * ff[2] + vz[j] * ff[3];
                float hv = PATH_W * (sc * (ff[0] * av[j] + bvv[j])
                                     + a1[j] * d3 * INV_SQRT3);
                hfrag[k][4 * h + j]     = (short)f2bf(hq);
                hfrag[k + 4][4 * h + j] = (short)f2bf(hv);
            }
        }
    }
    __syncthreads();   // W1 staged

    // ---- GEMM1: h1_pre[f][n] = b1 + sum_u W1[u][f] h[n][u]  (K=256) ----
    f32x4 acc[8];
    #pragma unroll
    for (int mt = 0; mt < 8; ++mt)
        acc[mt] = reinterpret_cast<const f32x4*>(b1)[mt * 4 + g];
    #pragma unroll
    for (int ks = 0; ks < 8; ++ks) {
        #pragma unroll
        for (int mt = 0; mt < 8; ++mt) {
            short8 a = *reinterpret_cast<const short8*>(
                smem + (mt * 8 + ks) * 1024 + lane * 16);
            acc[mt] = __builtin_amdgcn_mfma_f32_16x16x32_bf16(a, hfrag[ks], acc[mt], 0, 0, 0);
        }
    }
    __syncthreads();   // all waves done reading W1; its LDS is now free

    // ---- silu + transpose h1 into per-wave buffer (XOR-swizzled) ----
    char* tbuf = smem + wave * 4096;   // 16 nodes x 128 feats bf16
    #pragma unroll
    for (int mt = 0; mt < 8; ++mt) {
        float x0 = silu(acc[mt][0]), x1 = silu(acc[mt][1]);
        float x2 = silu(acc[mt][2]), x3 = silu(acc[mt][3]);
        unsigned int w0 = (unsigned int)f2bf(x0) | ((unsigned int)f2bf(x1) << 16);
        unsigned int w1 = (unsigned int)f2bf(x2) | ((unsigned int)f2bf(x3) << 16);
        int fs = (mt * 16 + g * 4) ^ (nl << 3);   // swizzle feat bits 3..6 by node
        *reinterpret_cast<unsigned int*>(tbuf + nl * 256 + fs * 2)     = w0;
        *reinterpret_cast<unsigned int*>(tbuf + nl * 256 + fs * 2 + 4) = w1;
    }
    __syncthreads();
    short8 h1frag[4];
    #pragma unroll
    for (int ks = 0; ks < 4; ++ks) {
        int F = (ks * 32 + g * 8) ^ (nl << 3);
        h1frag[ks] = *reinterpret_cast<const short8*>(tbuf + nl * 256 + F * 2);
    }
    __syncthreads();   // done reading transpose region

    // ---- stage W2 (32KB) + W3 (32KB) into LDS ----
    {
        const f32x4* src = reinterpret_cast<const f32x4*>(wp + 64 * 512);
        f32x4* dst = reinterpret_cast<f32x4*>(smem);
        #pragma unroll
        for (int i = 0; i < 8; ++i) dst[tid + i * 512] = src[tid + i * 512];
    }
    __syncthreads();

    // ---- GEMM2 (K=128) ----
    f32x4 acc2[8];
    #pragma unroll
    for (int mt = 0; mt < 8; ++mt)
        acc2[mt] = reinterpret_cast<const f32x4*>(b2)[mt * 4 + g];
    #pragma unroll
    for (int ks = 0; ks < 4; ++ks) {
        #pragma unroll
        for (int mt = 0; mt < 8; ++mt) {
            short8 a = *reinterpret_cast<const short8*>(
                smem + (mt * 4 + ks) * 1024 + lane * 16);
            acc2[mt] = __builtin_amdgcn_mfma_f32_16x16x32_bf16(a, h1frag[ks], acc2[mt], 0, 0, 0);
        }
    }
    __syncthreads();   // all waves done reading W2; overlay transpose there

    // ---- silu + transpose h2 ----
    #pragma unroll
    for (int mt = 0; mt < 8; ++mt) {
        float x0 = silu(acc2[mt][0]), x1 = silu(acc2[mt][1]);
        float x2 = silu(acc2[mt][2]), x3 = silu(acc2[mt][3]);
        unsigned int w0 = (unsigned int)f2bf(x0) | ((unsigned int)f2bf(x1) << 16);
        unsigned int w1 = (unsigned int)f2bf(x2) | ((unsigned int)f2bf(x3) << 16);
        int fs = (mt * 16 + g * 4) ^ (nl << 3);
        *reinterpret_cast<unsigned int*>(tbuf + nl * 256 + fs * 2)     = w0;
        *reinterpret_cast<unsigned int*>(tbuf + nl * 256 + fs * 2 + 4) = w1;
    }
    __syncthreads();
    short8 h2frag[4];
    #pragma unroll
    for (int ks = 0; ks < 4; ++ks) {
        int F = (ks * 32 + g * 8) ^ (nl << 3);
        h2frag[ks] = *reinterpret_cast<const short8*>(tbuf + nl * 256 + F * 2);
    }
    // W3 region [32K,64K) untouched by transposes -> no barrier needed here

    // ---- GEMM3 (K=128) ----
    f32x4 acc3[8];
    #pragma unroll
    for (int mt = 0; mt < 8; ++mt)
        acc3[mt] = reinterpret_cast<const f32x4*>(b3)[mt * 4 + g];
    #pragma unroll
    for (int ks = 0; ks < 4; ++ks) {
        #pragma unroll
        for (int mt = 0; mt < 8; ++mt) {
            short8 a = *reinterpret_cast<const short8*>(
                smem + 32768 + (mt * 4 + ks) * 1024 + lane * 16);
            acc3[mt] = __builtin_amdgcn_mfma_f32_16x16x32_bf16(a, h2frag[ks], acc3[mt], 0, 0, 0);
        }
    }

    // ---- epilogue: out[n] = silu(h3) . W4 + b4 (reduce over g-groups) ----
    float acc_out = 0.f;
    #pragma unroll
    for (int mt = 0; mt < 8; ++mt) {
        f32x4 w4v = reinterpret_cast<const f32x4*>(W4)[mt * 4 + g];
        acc_out += silu(acc3[mt][0]) * w4v[0];
        acc_out += silu(acc3[mt][1]) * w4v[1];
        acc_out += silu(acc3[mt][2]) * w4v[2];
        acc_out += silu(acc3[mt][3]) * w4v[3];
    }
    acc_out += __shfl_xor(acc_out, 16, 64);
    acc_out += __shfl_xor(acc_out, 32, 64);
    if (g == 0 && nd < N) out[nd] = acc_out + b4[0];
}

extern "C" void kernel_launch(void* const* d_in, const int* in_sizes, int n_in,
                              void* d_out, int out_size, void* d_ws, size_t ws_size,
                              hipStream_t stream) {
    const float* node_feats = (const float*)d_in[1];
    const float* field      = (const float*)d_in[5];
    const float* c0         = (const float*)d_in[6];
    const float* ci         = (const float*)d_in[7];
    const float* Wq0        = (const float*)d_in[8];
    const float* bq         = (const float*)d_in[9];
    const float* Wv0        = (const float*)d_in[10];
    const float* bv         = (const float*)d_in[11];
    const float* Wv1        = (const float*)d_in[12];
    const float* wq_s       = (const float*)d_in[13];
    // d_in[14] = wq_v is multiplied by q_up_v == 0 in the reference -> unused
    const float* wv_s       = (const float*)d_in[15];
    const float* wv_v       = (const float*)d_in[16];
    const float* W1         = (const float*)d_in[17];
    const float* b1         = (const float*)d_in[18];
    const float* W2         = (const float*)d_in[19];
    const float* b2         = (const float*)d_in[20];
    const float* W3         = (const float*)d_in[21];
    const float* b3         = (const float*)d_in[22];
    const float* W4         = (const float*)d_in[23];
    const float* b4         = (const float*)d_in[24];

    const int N = in_sizes[1] / 512;           // node_feats is [N, 4*C]
    float* vecs = (float*)d_ws;                 // 640 f32
    unsigned short* wp = (unsigned short*)((char*)d_ws + 4096);  // 128 frags x 1KB

    prep_all<<<129, 128, 0, stream>>>(Wq0, bq, Wv0, bv, Wv1, wq_s, wv_s, wv_v,
                                      W1, W2, W3, vecs, wp);
    const int blocks = (N + 127) / 128;
    fused_main<<<blocks, 512, 0, stream>>>(node_feats, field, c0, ci, vecs, wp,
                                           W4, b1, b2, b3, b4, (float*)d_out, N);
}